// Round 12
// baseline (207.519 us; speedup 1.0000x reference)
//
#include <hip/hip_runtime.h>
#include <stdint.h>

#define B_    8
#define N_    512
#define DIN   1024
#define DOUT  1024
#define L_    16
#define T_    4096

#define NKT (DIN / 32)          /* 32 K-tiles of BK=32 */
#define MT_MAX 544              /* 64-row M-tiles */
#define ZROW ((long)B_ * N_)    /* zero-row index in pooled_bf16 */

typedef __attribute__((ext_vector_type(8))) short short8;
typedef __attribute__((ext_vector_type(4))) float f32x4;

/* ws layout: pooled_bf16 (+zero row) | W' fragment-ordered bf16 | meta */
#define POOLED_ELEMS ((long)B_ * N_ * DIN + DIN)
#define WS_W_OFF     ((size_t)POOLED_ELEMS * 2)
#define WS_META_OFF  (WS_W_OFF + (size_t)L_ * DOUT * DIN * 2)

__device__ __forceinline__ unsigned short f2bf(float f) {
  unsigned u = __float_as_uint(f);
  u += 0x7FFFu + ((u >> 16) & 1u);   /* RNE */
  return (unsigned short)(u >> 16);
}

__device__ __forceinline__ void gload_lds16(const void* g, void* l) {
  __builtin_amdgcn_global_load_lds(
      (const __attribute__((address_space(1))) void*)g,
      (__attribute__((address_space(3))) void*)l, 16, 0, 0);
}

/* ---------------- kernel 1: convert pooled->bf16, W->W' fragment order ---- */
__global__ void k_convert(const float* __restrict__ pooled,
                          const float* __restrict__ W,
                          unsigned short* __restrict__ wsP,
                          unsigned short* __restrict__ wsW2) {
  const long np4 = (long)B_ * N_ * DIN / 4;
  const long nz4 = DIN / 4;
  const long nwu = (long)L_ * 64 * 32 * 64;
  long i = (long)blockIdx.x * blockDim.x + threadIdx.x;
  const long stride = (long)gridDim.x * blockDim.x;
  for (; i < np4 + nz4 + nwu; i += stride) {
    if (i < np4) {
      float4 v = ((const float4*)pooled)[i];
      ushort4 o = { f2bf(v.x), f2bf(v.y), f2bf(v.z), f2bf(v.w) };
      ((ushort4*)wsP)[i] = o;
    } else if (i < np4 + nz4) {
      ushort4 z = {0, 0, 0, 0};
      ((ushort4*)wsP)[i] = z;
    } else {
      long u = i - np4 - nz4;
      int ln = (int)(u & 63); long tmp = u >> 6;
      int kb = (int)(tmp & 31); tmp >>= 5;
      int cb = (int)(tmp & 63); int l = (int)(tmp >> 6);
      int r = cb * 16 + (ln & 15);
      int k = kb * 32 + (ln >> 4) * 8;
      const float* src = W + ((long)l * DOUT + r) * DIN + k;
      float4 v0 = *(const float4*)(src);
      float4 v1 = *(const float4*)(src + 4);
      ushort4 o0 = { f2bf(v0.x), f2bf(v0.y), f2bf(v0.z), f2bf(v0.w) };
      ushort4 o1 = { f2bf(v1.x), f2bf(v1.y), f2bf(v1.z), f2bf(v1.w) };
      ((ushort4*)wsW2)[u * 2]     = o0;
      ((ushort4*)wsW2)[u * 2 + 1] = o1;
    }
  }
}

/* ---------------- kernel 2: dedup prep (64-row tile granularity) ---------- */
__global__ void k_prep(const int* __restrict__ pidx,
                       unsigned* __restrict__ tlist,
                       int* __restrict__ goff, int* __restrict__ grows,
                       unsigned* __restrict__ table, int* __restrict__ ntiles) {
  __shared__ int sp[N_];
  __shared__ int cnt[L_], pos[L_];
  const int tid = threadIdx.x;
  if (tid < N_) sp[tid] = pidx[tid];
  if (tid < L_) cnt[tid] = 0;
  __syncthreads();

  int start = tid ? sp[tid - 1] + 1 : 0;
  int len = sp[tid] - start + 1;
  if (len < 0) len = 0;
  const int nfull = len < 15 ? len : 15;

  for (int l2 = 0; l2 < nfull; ++l2) atomicAdd(&cnt[l2], 1);
  if (len > 15) atomicAdd(&cnt[15], (len - 15 + 254) / 255);
  if (tid == N_ - 1) {
    int invlen = T_ - 1 - sp[N_ - 1];
    if (invlen > 0) atomicAdd(&cnt[15], (invlen + 254) / 255);
  }
  __syncthreads();
  if (tid == 0) {
    int off = 0;
    for (int l2 = 0; l2 < L_; ++l2) {
      pos[l2] = off; goff[l2] = off; grows[l2] = cnt[l2] * B_;
      off += cnt[l2];
    }
  }
  __syncthreads();

  for (int l2 = 0; l2 < nfull; ++l2) {
    int p = atomicAdd(&pos[l2], 1);
    tlist[p] = (unsigned)(start + l2) | ((unsigned)tid << 12) | (1u << 22);
  }
  if (len > 15) {
    int rem = len - 15, tt2 = start + 15;
    while (rem > 0) {
      int rr = rem > 255 ? 255 : rem;
      int p = atomicAdd(&pos[15], 1);
      tlist[p] = (unsigned)tt2 | ((unsigned)tid << 12) | ((unsigned)rr << 22);
      tt2 += rr; rem -= rr;
    }
  }
  if (tid == N_ - 1) {
    int tt2 = sp[N_ - 1] + 1;
    int rem = T_ - tt2;
    while (rem > 0) {
      int rr = rem > 255 ? 255 : rem;
      int p = atomicAdd(&pos[15], 1);
      tlist[p] = (unsigned)tt2 | (1023u << 12) | ((unsigned)rr << 22);
      tt2 += rr; rem -= rr;
    }
  }
  __syncthreads();
  if (tid == 0) {
    int tt = 0;
    for (int l2 = 0; l2 < L_; ++l2) {
      int rows = cnt[l2] * B_;
      for (int r0 = 0; r0 < rows; r0 += 64) table[tt++] = (unsigned)l2 | ((unsigned)r0 << 4);
    }
    *ntiles = tt;
  }
}

/* ---------------- kernel 3: BARRIER-FREE per-wave gather-GEMM --------------
   One wave = one 64x64 tile, fully independent (zero __syncthreads).
   A staged into wave-PRIVATE LDS (2x4KB) via gload_lds (wave-local ordering
   by counted vmcnt); B direct from W' (coalesced). Per phase: LDB(t),
   STG(t+1), vmcnt(4), 4 ds_read (R8 swizzle), 16 MFMA. ct=bid&15 fixed ->
   2 W' slices per XCD L2. R11 full-line epilogue through own LDS slice.    */
__global__ __launch_bounds__(256, 4)
void k_gemm(const unsigned short* __restrict__ wsP,
            const unsigned short* __restrict__ wsW2,
            const unsigned* __restrict__ tlist,
            const int* __restrict__ goff,
            const int* __restrict__ grows,
            const unsigned* __restrict__ table,
            const int* __restrict__ ntiles,
            float* __restrict__ out) {
  const int tid  = threadIdx.x;
  const int lane = tid & 63;
  const int w    = tid >> 6;
  const int ct   = blockIdx.x & 15;      /* fixed W' column slice per block */
  const int q    = blockIdx.x >> 4;      /* 0..31 */
  const int NTM  = *ntiles;

  __shared__ __align__(16) unsigned short As[4][2][64 * 32]; /* 32 KiB */

  /* wave-local staging slot swizzle (R8-verified involution) */
  const int sx4 = ((lane & 3) ^ (((lane >> 2) >> 1) & 3)) * 16;
  /* fragment read offsets (R8-verified, conflict-free) */
  const int arow = lane & 15;
  const int axr  = ((lane >> 4) ^ (((lane & 15) >> 1) & 3)) * 16;

#define STG(t_, bb) do { _Pragma("unroll") \
  for (int i_ = 0; i_ < 4; ++i_) \
    gload_lds16(aptr[i_] + (t_) * 64, (char*)As[w][bb] + i_ * 1024); } while (0)
#define LDB(t_) do { _Pragma("unroll") \
  for (int n_ = 0; n_ < 4; ++n_) \
    bf[n_] = *(const short8*)(wbase + n_ * (32 * 512) + (t_) * 512); } while (0)
#define DSA(bb) do { _Pragma("unroll") \
  for (int m_ = 0; m_ < 4; ++m_) \
    af[m_] = *(const short8*)((const char*)As[w][bb] + (arow + m_ * 16) * 64 + axr); } while (0)
#define VM(n_) asm volatile("s_waitcnt vmcnt(" #n_ ")" ::: "memory")
#define LGKM0  asm volatile("s_waitcnt lgkmcnt(0)" ::: "memory")
#define MMX do { _Pragma("unroll") for (int n_ = 0; n_ < 4; ++n_) \
  _Pragma("unroll") for (int m_ = 0; m_ < 4; ++m_) \
    acc[m_][n_] = __builtin_amdgcn_mfma_f32_16x16x32_bf16(af[m_], bf[n_], acc[m_][n_], 0, 0, 0); } while (0)

  for (int mtl = q * 4 + w; mtl < NTM; mtl += 128) {
    const unsigned te = table[mtl];
    const int l    = te & 15;
    const int row0 = (int)(te >> 4);
    const int toff = goff[l];
    const int rows = grows[l];

    /* gather pointers: instr i covers rows 16i..16i+15; lane -> row 16i+(lane>>2), slot lane&3 */
    const char* aptr[4];
#pragma unroll
    for (int i = 0; i < 4; ++i) {
      int rg = row0 + i * 16 + (lane >> 2);
      long re;
      if (rg < rows) {
        unsigned e = tlist[toff + (rg >> 3)];
        unsigned n = (e >> 12) & 0x3FF;
        int b = rg & 7;
        re = (n >= N_) ? ZROW * (long)DIN : ((long)(b * N_ + (int)n)) * DIN;
      } else re = ZROW * (long)DIN;
      aptr[i] = (const char*)(wsP + re) + sx4;
    }
    const unsigned short* wbase =
        wsW2 + (((long)l * 64 + ct * 4) * 32) * 512 + lane * 8;

    f32x4 acc[4][4];
#pragma unroll
    for (int m = 0; m < 4; ++m)
#pragma unroll
      for (int n = 0; n < 4; ++n)
        acc[m][n] = (f32x4){0.f, 0.f, 0.f, 0.f};

    short8 af[4], bf[4];

    STG(0, 0);                               /* prologue: A(0) -> buf0 */
#pragma unroll
    for (int j = 0; j < NKT / 2; ++j) {
      const int t0 = 2 * j, t1 = 2 * j + 1;
      /* phase t0: read buf0 */
      LDB(t0);
      STG(t1, 1);
      VM(4);                                 /* drains A(t0)+B(t0); A(t1) in flight */
      DSA(0); LGKM0; MMX;
      /* phase t1: read buf1 */
      LDB(t1);
      if (t1 + 1 < NKT) { STG(t1 + 1, 0); VM(4); }
      else              { VM(0); }
      DSA(1); LGKM0; MMX;
    }

    /* ---- epilogue: full-line stores via wave-private LDS transpose ---- */
    {
      float* sc = (float*)As[w];             /* 2048 f32; need 16*68=1088 */
#pragma unroll
      for (int m = 0; m < 4; ++m) {
#pragma unroll
        for (int n = 0; n < 4; ++n)
#pragma unroll
          for (int jj = 0; jj < 4; ++jj)
            sc[((lane >> 4) * 4 + jj) * 68 + n * 16 + (lane & 15)] = acc[m][n][jj];
        LGKM0;
#pragma unroll
        for (int r0 = 0; r0 < 16; r0 += 4) {
          int rtl = r0 + (lane >> 4);
          float4 v = *(const float4*)(sc + rtl * 68 + (lane & 15) * 4);
          int rg = row0 + m * 16 + rtl;
          if (rg < rows) {
            unsigned e = tlist[toff + (rg >> 3)];
            int b = rg & 7;
            int tt = (int)(e & 0xFFFu);
            int rep = (int)(e >> 22);
            float* p = out + ((long)b * T_ + tt) * DOUT + ct * 64 + (lane & 15) * 4;
            for (int r = 0; r < rep; ++r) { *(float4*)p = v; p += DOUT; }
          }
        }
        LGKM0;
      }
    }
  }
#undef STG
#undef LDB
#undef DSA
#undef VM
#undef LGKM0
#undef MMX
}

/* ---------------- launch ---------------- */
extern "C" void kernel_launch(void* const* d_in, const int* in_sizes, int n_in,
                              void* d_out, int out_size, void* d_ws, size_t ws_size,
                              hipStream_t stream) {
  const float* pooled = (const float*)d_in[0];
  const float* W      = (const float*)d_in[1];
  const int*   pidx   = (const int*)d_in[2];
  float* out = (float*)d_out;

  char* ws = (char*)d_ws;
  unsigned short* wsP  = (unsigned short*)(ws);
  unsigned short* wsW2 = (unsigned short*)(ws + WS_W_OFF);
  int* meta  = (int*)(ws + WS_META_OFF);
  unsigned* tlist = (unsigned*)meta;
  int* goff  = meta + 8 * T_;
  int* grows = meta + 8 * T_ + 16;
  unsigned* table = (unsigned*)(meta + 8 * T_ + 32);
  int* ntiles = meta + 8 * T_ + 32 + MT_MAX;

  k_prep<<<1, 512, 0, stream>>>(pidx, tlist, goff, grows, table, ntiles);
  k_convert<<<2048, 256, 0, stream>>>(pooled, W, wsP, wsW2);
  k_gemm<<<512, 256, 0, stream>>>(wsP, wsW2, tlist, goff, grows, table,
                                  ntiles, out);
}

// Round 13
// 195.200 us; speedup vs baseline: 1.0631x; 1.0631x over previous
//
#include <hip/hip_runtime.h>
#include <stdint.h>

#define B_    8
#define N_    512
#define DIN   1024
#define DOUT  1024
#define L_    16
#define T_    4096

#define BM 128
#define BN 128
#define BK 32
#define NB (DOUT / BN)          /* 8 */
#define NKT (DIN / BK)          /* 32 K-tiles */
#define MT_MAX 288
#define ZROW ((long)B_ * N_)    /* zero-row index in pooled_bf16 */

typedef __attribute__((ext_vector_type(8))) short short8;
typedef __attribute__((ext_vector_type(4))) float f32x4;

/* ws layout: pooled_bf16 (+zero row) | W' fragment-ordered bf16 | meta */
#define POOLED_ELEMS ((long)B_ * N_ * DIN + DIN)
#define WS_W_OFF     ((size_t)POOLED_ELEMS * 2)
#define WS_META_OFF  (WS_W_OFF + (size_t)L_ * DOUT * DIN * 2)

__device__ __forceinline__ unsigned short f2bf(float f) {
  unsigned u = __float_as_uint(f);
  u += 0x7FFFu + ((u >> 16) & 1u);   /* RNE */
  return (unsigned short)(u >> 16);
}

__device__ __forceinline__ void gload_lds16(const void* g, void* l) {
  __builtin_amdgcn_global_load_lds(
      (const __attribute__((address_space(1))) void*)g,
      (__attribute__((address_space(3))) void*)l, 16, 0, 0);
}

/* ---------------- kernel 1: convert pooled->bf16, W->W' fragment order ---- */
__global__ void k_convert(const float* __restrict__ pooled,
                          const float* __restrict__ W,
                          unsigned short* __restrict__ wsP,
                          unsigned short* __restrict__ wsW2) {
  const long np4 = (long)B_ * N_ * DIN / 4;
  const long nz4 = DIN / 4;
  const long nwu = (long)L_ * 64 * 32 * 64;
  long i = (long)blockIdx.x * blockDim.x + threadIdx.x;
  const long stride = (long)gridDim.x * blockDim.x;
  for (; i < np4 + nz4 + nwu; i += stride) {
    if (i < np4) {
      float4 v = ((const float4*)pooled)[i];
      ushort4 o = { f2bf(v.x), f2bf(v.y), f2bf(v.z), f2bf(v.w) };
      ((ushort4*)wsP)[i] = o;
    } else if (i < np4 + nz4) {
      ushort4 z = {0, 0, 0, 0};
      ((ushort4*)wsP)[i] = z;
    } else {
      long u = i - np4 - nz4;
      int ln = (int)(u & 63); long tmp = u >> 6;
      int kb = (int)(tmp & 31); tmp >>= 5;
      int cb = (int)(tmp & 63); int l = (int)(tmp >> 6);
      int r = cb * 16 + (ln & 15);
      int k = kb * 32 + (ln >> 4) * 8;
      const float* src = W + ((long)l * DOUT + r) * DIN + k;
      float4 v0 = *(const float4*)(src);
      float4 v1 = *(const float4*)(src + 4);
      ushort4 o0 = { f2bf(v0.x), f2bf(v0.y), f2bf(v0.z), f2bf(v0.w) };
      ushort4 o1 = { f2bf(v1.x), f2bf(v1.y), f2bf(v1.z), f2bf(v1.w) };
      ((ushort4*)wsW2)[u * 2]     = o0;
      ((ushort4*)wsW2)[u * 2 + 1] = o1;
    }
  }
}

/* ---------------- kernel 2: dedup prep (verbatim R8) ---------------- */
__global__ void k_prep(const int* __restrict__ pidx,
                       unsigned* __restrict__ tlist,
                       int* __restrict__ goff, int* __restrict__ grows,
                       unsigned* __restrict__ table, int* __restrict__ ntiles) {
  __shared__ int sp[N_];
  __shared__ int cnt[L_], pos[L_];
  const int tid = threadIdx.x;
  if (tid < N_) sp[tid] = pidx[tid];
  if (tid < L_) cnt[tid] = 0;
  __syncthreads();

  int start = tid ? sp[tid - 1] + 1 : 0;
  int len = sp[tid] - start + 1;
  if (len < 0) len = 0;
  const int nfull = len < 15 ? len : 15;

  for (int l2 = 0; l2 < nfull; ++l2) atomicAdd(&cnt[l2], 1);
  if (len > 15) atomicAdd(&cnt[15], (len - 15 + 254) / 255);
  if (tid == N_ - 1) {
    int invlen = T_ - 1 - sp[N_ - 1];
    if (invlen > 0) atomicAdd(&cnt[15], (invlen + 254) / 255);
  }
  __syncthreads();
  if (tid == 0) {
    int off = 0;
    for (int l2 = 0; l2 < L_; ++l2) {
      pos[l2] = off; goff[l2] = off; grows[l2] = cnt[l2] * B_;
      off += cnt[l2];
    }
  }
  __syncthreads();

  for (int l2 = 0; l2 < nfull; ++l2) {
    int p = atomicAdd(&pos[l2], 1);
    tlist[p] = (unsigned)(start + l2) | ((unsigned)tid << 12) | (1u << 22);
  }
  if (len > 15) {
    int rem = len - 15, tt2 = start + 15;
    while (rem > 0) {
      int rr = rem > 255 ? 255 : rem;
      int p = atomicAdd(&pos[15], 1);
      tlist[p] = (unsigned)tt2 | ((unsigned)tid << 12) | ((unsigned)rr << 22);
      tt2 += rr; rem -= rr;
    }
  }
  if (tid == N_ - 1) {
    int tt2 = sp[N_ - 1] + 1;
    int rem = T_ - tt2;
    while (rem > 0) {
      int rr = rem > 255 ? 255 : rem;
      int p = atomicAdd(&pos[15], 1);
      tlist[p] = (unsigned)tt2 | (1023u << 12) | ((unsigned)rr << 22);
      tt2 += rr; rem -= rr;
    }
  }
  __syncthreads();
  if (tid == 0) {
    int tt = 0;
    for (int l2 = 0; l2 < L_; ++l2) {
      int rows = cnt[l2] * B_;
      for (int r0 = 0; r0 < rows; r0 += BM) table[tt++] = (unsigned)l2 | ((unsigned)r0 << 4);
    }
    *ntiles = tt;
  }
}

/* ---------------- kernel 3: A-via-LDS, B-direct, STAGGERED pipeline --------
   R10 base. Change: ds_read (af) for buffer b issues immediately after the
   __syncthreads that publishes b — one MFMA-phase ahead of use — so LDS
   latency hides under the other tile's MFMA + load issue. Double-buffered
   af regs. 4 blocks/CU target.                                              */
__global__ __launch_bounds__(256, 4)
void k_gemm(const unsigned short* __restrict__ wsP,
            const unsigned short* __restrict__ wsW2,
            const unsigned* __restrict__ tlist,
            const int* __restrict__ goff,
            const int* __restrict__ grows,
            const unsigned* __restrict__ table,
            const int* __restrict__ ntiles,
            float* __restrict__ out) {
  const int bid = blockIdx.x;
  const int mt = bid >> 3;
  const int nt = bid & 7;            /* nt == XCD: W' slice pinned per L2 */
  if (mt >= *ntiles) return;

  const unsigned te = table[mt];
  const int l    = te & 15;
  const int row0 = (int)(te >> 4);
  const int toff = goff[l];
  const int rows = grows[l];

  __shared__ __align__(16) unsigned short As[2][BM * BK];  /* 2 x 8 KiB */

  const int tid  = threadIdx.x;
  const int lane = tid & 63;
  const int w    = tid >> 6;      /* 0..3 */
  const int wm   = w >> 1;
  const int wn   = w & 1;

  /* ---- A staging (verbatim R8: inverse-swizzled source slot) ---- */
  const int srow = tid >> 2;                       /* 0..63 */
  const int sx4  = ((tid & 3) ^ ((srow >> 1) & 3)) * 16;
  const char* aptr0;
  const char* aptr1;
  {
    long re[2];
#pragma unroll
    for (int r = 0; r < 2; ++r) {
      int rg = row0 + r * 64 + srow;
      if (rg < rows) {
        unsigned e = tlist[toff + (rg >> 3)];
        unsigned n = (e >> 12) & 0x3FF;
        int b = rg & 7;
        re[r] = (n >= N_) ? ZROW * (long)DIN
                          : ((long)(b * N_ + (int)n)) * DIN;
      } else re[r] = ZROW * (long)DIN;
    }
    aptr0 = (const char*)(wsP + re[0]) + sx4;
    aptr1 = (const char*)(wsP + re[1]) + sx4;
  }

#define STG_A(t_, sb) do { \
  gload_lds16(aptr0 + (t_) * 64, (char*)As[sb] + w * 1024); \
  gload_lds16(aptr1 + (t_) * 64, (char*)As[sb] + 4096 + w * 1024); } while (0)

  /* ---- A fragment read offsets (verbatim R8, conflict-free) ---- */
  const int arow = wm * 64 + (lane & 15);
  const int axr  = ((lane >> 4) ^ (((lane & 15) >> 1) & 3)) * 16;

  /* ---- B direct: W'[l][cb][kb][lane*8], cb = nt*8 + wn*4 + n ---- */
  const unsigned short* wbase =
      wsW2 + (((long)l * 64 + nt * 8 + wn * 4) * 32) * 512 + lane * 8;
#define LDB(dst, t_) do { _Pragma("unroll") \
  for (int n_ = 0; n_ < 4; ++n_) \
    dst[n_] = *(const short8*)(wbase + n_ * (32 * 512) + (t_) * 512); } while (0)

#define DSA(dst, bb) do { _Pragma("unroll") \
  for (int m_ = 0; m_ < 4; ++m_) \
    dst[m_] = *(const short8*)((const char*)As[bb] + (arow + m_ * 16) * 64 + axr); } while (0)

#define MM(AF, BF) do { \
  __builtin_amdgcn_s_setprio(1); \
  _Pragma("unroll") for (int n_ = 0; n_ < 4; ++n_) \
    _Pragma("unroll") for (int m_ = 0; m_ < 4; ++m_) \
      acc[m_][n_] = __builtin_amdgcn_mfma_f32_16x16x32_bf16(AF[m_], BF[n_], acc[m_][n_], 0, 0, 0); \
  __builtin_amdgcn_s_setprio(0); } while (0)

  f32x4 acc[4][4];
#pragma unroll
  for (int m = 0; m < 4; ++m)
#pragma unroll
    for (int n = 0; n < 4; ++n)
      acc[m][n] = (f32x4){0.f, 0.f, 0.f, 0.f};

  short8 af_a[4], af_b[4], bf_a[4], bf_b[4];

  /* ---- prologue: A(0)->buf0, B(0)->regs; publish; pre-issue af(buf0) ---- */
  STG_A(0, 0);
  LDB(bf_a, 0);
  __syncthreads();
  DSA(af_a, 0);

#pragma unroll
  for (int j = 0; j < NKT / 2; ++j) {
    const int t0 = 2 * j, t1 = 2 * j + 1;
    /* phase t0: operands (af_a, bf_a) already issued; fill buf1 + bf_b */
    STG_A(t1, 1);
    LDB(bf_b, t1);
    MM(af_a, bf_a);                  /* compiler waits lgkm/vmcnt as needed */
    __syncthreads();                 /* publishes buf1 (t1) */
    DSA(af_b, 1);                    /* early-issue t1 A-frags */
    /* phase t1: fill buf0 (t0+2) + bf_a */
    if (t0 + 2 < NKT) { STG_A(t0 + 2, 0); LDB(bf_a, t0 + 2); }
    MM(af_b, bf_b);
    __syncthreads();                 /* publishes buf0 (t0+2) */
    DSA(af_a, 0);                    /* early-issue t0+2 A-frags (dead on last iter) */
  }

  /* ---- epilogue: C/D col=lane&15, row=(lane>>4)*4+j; rep-write (R10) ---- */
#pragma unroll
  for (int m = 0; m < 4; ++m) {
#pragma unroll
    for (int jj = 0; jj < 4; ++jj) {
      int rt = wm * 64 + m * 16 + (lane >> 4) * 4 + jj;
      int rg = row0 + rt;
      if (rg >= rows) continue;
      unsigned e = tlist[toff + (rg >> 3)];
      int b = rg & 7;
      int t0 = (int)(e & 0xFFFu);
      int rep = (int)(e >> 22);
      float* orow = out + ((long)b * T_ + t0) * DOUT + nt * BN + wn * 64 + (lane & 15);
      for (int r = 0; r < rep; ++r) {
#pragma unroll
        for (int n = 0; n < 4; ++n)
          orow[n * 16] = acc[m][n][jj];
        orow += DOUT;
      }
    }
  }
#undef STG_A
#undef LDB
#undef DSA
#undef MM
}

/* ---------------- launch ---------------- */
extern "C" void kernel_launch(void* const* d_in, const int* in_sizes, int n_in,
                              void* d_out, int out_size, void* d_ws, size_t ws_size,
                              hipStream_t stream) {
  const float* pooled = (const float*)d_in[0];
  const float* W      = (const float*)d_in[1];
  const int*   pidx   = (const int*)d_in[2];
  float* out = (float*)d_out;

  char* ws = (char*)d_ws;
  unsigned short* wsP  = (unsigned short*)(ws);
  unsigned short* wsW2 = (unsigned short*)(ws + WS_W_OFF);
  int* meta  = (int*)(ws + WS_META_OFF);
  unsigned* tlist = (unsigned*)meta;
  int* goff  = meta + 8 * T_;
  int* grows = meta + 8 * T_ + 16;
  unsigned* table = (unsigned*)(meta + 8 * T_ + 32);
  int* ntiles = meta + 8 * T_ + 32 + MT_MAX;

  k_prep<<<1, 512, 0, stream>>>(pidx, tlist, goff, grows, table, ntiles);
  k_convert<<<2048, 256, 0, stream>>>(pooled, W, wsP, wsW2);
  k_gemm<<<MT_MAX * NB, 256, 0, stream>>>(wsP, wsW2, tlist, goff, grows, table,
                                          ntiles, out);
}